// Round 8
// baseline (114.109 us; speedup 1.0000x reference)
//
#include <hip/hip_runtime.h>

#define B_N 4096
#define D_K 256
#define BT  128                     // block tile (128x128)
#define NT  (B_N / BT)              // 32
#define NBLK (NT * (NT + 1) / 2)    // 528 triangular blocks
#define BK  32                      // k-chunk (64 B/row)
#define NKITER (D_K / BK)           // 8

typedef __bf16 bf16x8 __attribute__((ext_vector_type(8)));
typedef float  floatx4 __attribute__((ext_vector_type(4)));

typedef __attribute__((address_space(3))) unsigned int lds_u32;
typedef const __attribute__((address_space(1))) unsigned int glb_u32;

__device__ inline unsigned short f2bf(float f) {
    unsigned int u = __float_as_uint(f);
    return (unsigned short)((u + 0x7FFFu + ((u >> 16) & 1u)) >> 16);
}

// ---------------------------------------------------------------------------
// prep: fp32 squared norms (exact), packed labels, bf16 copy of F,
//       and zero the completion counter for pair's last-block reduce.
// ---------------------------------------------------------------------------
__global__ __launch_bounds__(256) void prep_kernel(const float* __restrict__ F,
                                                   const int* __restrict__ labels,
                                                   float* __restrict__ sq,
                                                   int* __restrict__ plab,
                                                   unsigned short* __restrict__ Fb,
                                                   unsigned int* __restrict__ counter) {
    if (blockIdx.x == 0 && threadIdx.x == 0) *counter = 0;
    int row  = blockIdx.x * 4 + (threadIdx.x >> 6);
    int lane = threadIdx.x & 63;
    const float4* fp = reinterpret_cast<const float4*>(F + (size_t)row * D_K);
    float4 v = fp[lane];
    ushort4 b;
    b.x = f2bf(v.x); b.y = f2bf(v.y); b.z = f2bf(v.z); b.w = f2bf(v.w);
    reinterpret_cast<ushort4*>(Fb + (size_t)row * D_K)[lane] = b;
    float s = v.x * v.x + v.y * v.y + v.z * v.z + v.w * v.w;
#pragma unroll
    for (int off = 32; off > 0; off >>= 1) s += __shfl_down(s, off);
    if (lane == 0) {
        sq[row] = s;
        const int* lp = labels + (size_t)row * 3;
        plab[row] = lp[0] | (lp[1] << 3) | (lp[2] << 6);
    }
}

// ---------------------------------------------------------------------------
// pair: 128x128 tile / block (4 waves, 64x64 quadrant each).
// BK=32 DOUBLE-BUFFERED LDS (2 x 16 KB = 32 KB total -> up to 4 blocks/CU),
// one barrier per k-iter; stage(it+1) issued AFTER the barrier so its loads
// stay in flight across compute(it) and the next barrier's vmcnt drain is
// pre-hidden.
// Layout: row = 64 B = 4 chunks of 16 B; LDS(row,phys) holds global chunk
// phys ^ (row&3). Frag read starts spread uniformly over the 8 16B bank
// groups -> conflict-free (same mechanism as R4's measured 0).
// C/D map (verified): col = lane&15, row = (lane>>4)*4 + reg.
// Final: last block to finish sums partials and writes out (no reduce kernel).
// ---------------------------------------------------------------------------
__global__ __launch_bounds__(256) void pair_kernel(const unsigned short* __restrict__ Fb,
                                                   const float* __restrict__ sq,
                                                   const int* __restrict__ plab,
                                                   float* __restrict__ partials,
                                                   unsigned int* __restrict__ counter,
                                                   float* __restrict__ out) {
    __shared__ unsigned short As[2][BT * BK];   // 2 x 8 KB
    __shared__ unsigned short Bs[2][BT * BK];   // 2 x 8 KB
    __shared__ float red[4];
    __shared__ bool  amLast;

    int idx = blockIdx.x, bi = 0;
    while (idx >= NT - bi) { idx -= NT - bi; ++bi; }
    const int bj = bi + idx;

    const int i0   = bi * BT;
    const int j0   = bj * BT;
    const int wave = threadIdx.x >> 6;
    const int lane = threadIdx.x & 63;
    const int lrow = lane & 15;
    const int kgrp = lane >> 4;          // 0..3
    const int wy   = wave >> 1;
    const int wx   = wave & 1;
    const int r0   = wy * 64;
    const int c0   = wx * 64;

    floatx4 acc[4][4];
#pragma unroll
    for (int tm = 0; tm < 4; ++tm)
#pragma unroll
        for (int tn = 0; tn < 4; ++tn) acc[tm][tn] = floatx4{0.f, 0.f, 0.f, 0.f};

    const int srow_in = lane >> 2;       // 0..15 within one staging instr
    const int sphys   = lane & 3;        // physical 16B chunk within row

    const char* gA = (const char*)(Fb + (size_t)i0 * D_K);
    const char* gB = (const char*)(Fb + (size_t)j0 * D_K);

    // stage k-chunk `it` into buffer `buf` (8 KB per matrix = 8 instrs;
    // each wave issues 2 A + 2 B)
    auto stage = [&](int it, int buf) {
        const size_t kbyte = (size_t)it * BK * 2;    // 64 B per k-chunk row
        char* lAs = (char*)As[buf];
        char* lBs = (char*)Bs[buf];
#pragma unroll
        for (int q = 0; q < 2; ++q) {
            int instr = wave * 2 + q;                // 0..7
            int row   = instr * 16 + srow_in;        // 0..127
            int chunk = sphys ^ (row & 3);
            __builtin_amdgcn_global_load_lds(
                (glb_u32*)(gA + (size_t)row * (D_K * 2) + kbyte + chunk * 16),
                (lds_u32*)(lAs + instr * 1024), 16, 0, 0);
            __builtin_amdgcn_global_load_lds(
                (glb_u32*)(gB + (size_t)row * (D_K * 2) + kbyte + chunk * 16),
                (lds_u32*)(lBs + instr * 1024), 16, 0, 0);
        }
    };

    stage(0, 0);

    for (int it = 0; it < NKITER; ++it) {
        const int cur = it & 1;
        __syncthreads();                 // buf[cur] ready; drains loads issued
                                         // a full iter ago (pre-hidden)
        if (it + 1 < NKITER) stage(it + 1, cur ^ 1);

        const char* cAs = (const char*)As[cur];
        const char* cBs = (const char*)Bs[cur];
        bf16x8 a[4], b[4];
#pragma unroll
        for (int tm = 0; tm < 4; ++tm) {
            int row = r0 + tm * 16 + lrow;
            a[tm] = *reinterpret_cast<const bf16x8*>(
                cAs + row * 64 + ((kgrp ^ (row & 3)) * 16));
        }
#pragma unroll
        for (int tn = 0; tn < 4; ++tn) {
            int row = c0 + tn * 16 + lrow;
            b[tn] = *reinterpret_cast<const bf16x8*>(
                cBs + row * 64 + ((kgrp ^ (row & 3)) * 16));
        }
#pragma unroll
        for (int tm = 0; tm < 4; ++tm)
#pragma unroll
            for (int tn = 0; tn < 4; ++tn)
                acc[tm][tn] = __builtin_amdgcn_mfma_f32_16x16x32_bf16(
                    a[tm], b[tn], acc[tm][tn], 0, 0, 0);
    }

    // epilogue: d2 = sq_i + sq_j - 2g; contrastive term; strict j>i mask
    float sqj[4];
    int   lj[4];
#pragma unroll
    for (int tn = 0; tn < 4; ++tn) {
        int j = j0 + c0 + tn * 16 + lrow;
        sqj[tn] = sq[j];
        lj[tn]  = plab[j];
    }

    float local = 0.f;
#pragma unroll
    for (int tm = 0; tm < 4; ++tm) {
#pragma unroll
        for (int r = 0; r < 4; ++r) {
            int i = i0 + r0 + tm * 16 + kgrp * 4 + r;
            float sqi = sq[i];
            int   li  = plab[i];
#pragma unroll
            for (int tn = 0; tn < 4; ++tn) {
                int j = j0 + c0 + tn * 16 + lrow;
                if (j > i) {
                    float d2 = fmaxf(sqi + sqj[tn] - 2.f * acc[tm][tn][r], 0.f);
                    float dist = sqrtf(d2);
                    local += (li == lj[tn]) ? (0.5f * dist)
                                            : (0.5f * fmaxf(1.f - dist, 0.f));
                }
            }
        }
    }

#pragma unroll
    for (int off = 32; off > 0; off >>= 1) local += __shfl_down(local, off);
    if (lane == 0) red[wave] = local;
    __syncthreads();
    if (threadIdx.x == 0)
        partials[blockIdx.x] = red[0] + red[1] + red[2] + red[3];

    // last block to finish does the final reduction (release/acquire fences)
    __threadfence();
    if (threadIdx.x == 0) {
        unsigned int old = atomicAdd(counter, 1u);
        amLast = (old == NBLK - 1);
    }
    __syncthreads();
    if (amLast) {
        __threadfence();
        const volatile float* vp = (const volatile float*)partials;
        float s = 0.f;
        for (int i = threadIdx.x; i < NBLK; i += 256) s += vp[i];
#pragma unroll
        for (int off = 32; off > 0; off >>= 1) s += __shfl_down(s, off);
        if (lane == 0) red[wave] = s;
        __syncthreads();
        if (threadIdx.x == 0)
            out[0] = (red[0] + red[1] + red[2] + red[3]) * (1.0f / B_N);
    }
}

extern "C" void kernel_launch(void* const* d_in, const int* in_sizes, int n_in,
                              void* d_out, int out_size, void* d_ws, size_t ws_size,
                              hipStream_t stream) {
    const float* F      = (const float*)d_in[0];
    const int*   labels = (const int*)d_in[1];
    float* out = (float*)d_out;

    float*          sq    = (float*)d_ws;                                 // 16 KB
    int*            plab  = (int*)((char*)d_ws + B_N * 4);                // 16 KB
    float*          parts = (float*)((char*)d_ws + 2 * B_N * 4);          // ~2 KB
    unsigned int*   cnt   = (unsigned int*)((char*)d_ws + 36 * 1024);     // 4 B
    unsigned short* Fb    = (unsigned short*)((char*)d_ws + 65536);       // 2 MB

    prep_kernel<<<B_N / 4, 256, 0, stream>>>(F, labels, sq, plab, Fb, cnt);
    pair_kernel<<<NBLK, 256, 0, stream>>>(Fb, sq, plab, parts, cnt, out);
}

// Round 9
// 75.539 us; speedup vs baseline: 1.5106x; 1.5106x over previous
//
#include <hip/hip_runtime.h>

#define B_N 4096
#define D_K 256
#define BT  64                      // block tile (64x64)
#define NT  (B_N / BT)              // 64
#define NBLK (NT * (NT + 1) / 2)    // 2080 triangular blocks
#define BK  64                      // k-chunk (128 B/row)
#define NKITER (D_K / BK)           // 4

typedef __bf16 bf16x8 __attribute__((ext_vector_type(8)));
typedef float  floatx4 __attribute__((ext_vector_type(4)));

typedef __attribute__((address_space(3))) unsigned int lds_u32;
typedef const __attribute__((address_space(1))) unsigned int glb_u32;

__device__ inline unsigned short f2bf(float f) {
    unsigned int u = __float_as_uint(f);
    return (unsigned short)((u + 0x7FFFu + ((u >> 16) & 1u)) >> 16);
}

// ---------------------------------------------------------------------------
// prep: fp32 squared norms (exact), packed labels, bf16 copy of F.
// ---------------------------------------------------------------------------
__global__ __launch_bounds__(256) void prep_kernel(const float* __restrict__ F,
                                                   const int* __restrict__ labels,
                                                   float* __restrict__ sq,
                                                   int* __restrict__ plab,
                                                   unsigned short* __restrict__ Fb) {
    int row  = blockIdx.x * 4 + (threadIdx.x >> 6);
    int lane = threadIdx.x & 63;
    const float4* fp = reinterpret_cast<const float4*>(F + (size_t)row * D_K);
    float4 v = fp[lane];
    ushort4 b;
    b.x = f2bf(v.x); b.y = f2bf(v.y); b.z = f2bf(v.z); b.w = f2bf(v.w);
    reinterpret_cast<ushort4*>(Fb + (size_t)row * D_K)[lane] = b;
    float s = v.x * v.x + v.y * v.y + v.z * v.z + v.w * v.w;
#pragma unroll
    for (int off = 32; off > 0; off >>= 1) s += __shfl_down(s, off);
    if (lane == 0) {
        sq[row] = s;
        const int* lp = labels + (size_t)row * 3;
        plab[row] = lp[0] | (lp[1] << 3) | (lp[2] << 6);
    }
}

// ---------------------------------------------------------------------------
// pair: 64x64 tile per 256-thread block (4 waves, 32x32 quadrant each).
// Grid = 2080 blocks -> ~8 blocks/CU resident (32 waves/CU): 8 independent
// barrier groups per CU so barrier/vmcnt drains of one block overlap other
// blocks' compute (m114 co-scheduling) — attacks the measured 18% occupancy.
// LDS 16 KB single-buffered, R4-verified staging: global_load_lds width-16,
// rows of 128 B = 8 chunks, LDS(row,phys) holds global chunk phys^(row&7)
// (measured 0 bank conflicts). C/D map: col=lane&15, row=(lane>>4)*4+reg.
// Diagonal blocks (bi==bj) alias B tile to A tile (skip half the staging).
// ---------------------------------------------------------------------------
__global__ __launch_bounds__(256) void pair_kernel(const unsigned short* __restrict__ Fb,
                                                   const float* __restrict__ sq,
                                                   const int* __restrict__ plab,
                                                   float* __restrict__ partials) {
    __shared__ unsigned short smem[2 * BT * BK];   // A: 8 KB, B: 8 KB
    __shared__ float red[4];

    int idx = blockIdx.x, bi = 0;
    while (idx >= NT - bi) { idx -= NT - bi; ++bi; }
    const int bj = bi + idx;
    const bool diag = (bi == bj);

    const int i0   = bi * BT;
    const int j0   = bj * BT;
    const int wave = threadIdx.x >> 6;
    const int lane = threadIdx.x & 63;
    const int lrow = lane & 15;
    const int kgrp = lane >> 4;          // 0..3
    const int r0   = (wave >> 1) * 32;   // quadrant row
    const int c0   = (wave & 1) * 32;    // quadrant col

    char* lAs = (char*)smem;
    char* lBs = diag ? lAs : (char*)(smem + BT * BK);

    floatx4 acc[2][2];
#pragma unroll
    for (int tm = 0; tm < 2; ++tm)
#pragma unroll
        for (int tn = 0; tn < 2; ++tn) acc[tm][tn] = floatx4{0.f, 0.f, 0.f, 0.f};

    const int srow_in = lane >> 3;       // 0..7 within one staging instr
    const int sphys   = lane & 7;        // physical 16B chunk within row

    const char* gA = (const char*)(Fb + (size_t)i0 * D_K);
    const char* gB = (const char*)(Fb + (size_t)j0 * D_K);

    for (int it = 0; it < NKITER; ++it) {
        const size_t kbyte = (size_t)it * BK * 2;   // 128 B per row per chunk
        // 8 staging instrs per matrix (64 rows x 128 B); each wave issues 2
#pragma unroll
        for (int q = 0; q < 2; ++q) {
            int instr = wave * 2 + q;               // 0..7
            int row   = instr * 8 + srow_in;        // 0..63
            int chunk = sphys ^ (row & 7);
            __builtin_amdgcn_global_load_lds(
                (glb_u32*)(gA + (size_t)row * (D_K * 2) + kbyte + chunk * 16),
                (lds_u32*)(lAs + instr * 1024), 16, 0, 0);
            if (!diag)
                __builtin_amdgcn_global_load_lds(
                    (glb_u32*)(gB + (size_t)row * (D_K * 2) + kbyte + chunk * 16),
                    (lds_u32*)(lBs + instr * 1024), 16, 0, 0);
        }
        __syncthreads();

#pragma unroll
        for (int ks = 0; ks < 2; ++ks) {
            bf16x8 a[2], b[2];
            const int c = ks * 4 + kgrp;            // logical chunk 0..7
#pragma unroll
            for (int tm = 0; tm < 2; ++tm) {
                int row = r0 + tm * 16 + lrow;
                a[tm] = *reinterpret_cast<const bf16x8*>(
                    lAs + row * 128 + ((c ^ (row & 7)) * 16));
            }
#pragma unroll
            for (int tn = 0; tn < 2; ++tn) {
                int row = c0 + tn * 16 + lrow;
                b[tn] = *reinterpret_cast<const bf16x8*>(
                    lBs + row * 128 + ((c ^ (row & 7)) * 16));
            }
#pragma unroll
            for (int tm = 0; tm < 2; ++tm)
#pragma unroll
                for (int tn = 0; tn < 2; ++tn)
                    acc[tm][tn] = __builtin_amdgcn_mfma_f32_16x16x32_bf16(
                        a[tm], b[tn], acc[tm][tn], 0, 0, 0);
        }
        __syncthreads();
    }

    // epilogue: d2 = sq_i + sq_j - 2g; contrastive term; strict j>i mask
    float sqj[2];
    int   lj[2];
#pragma unroll
    for (int tn = 0; tn < 2; ++tn) {
        int j = j0 + c0 + tn * 16 + lrow;
        sqj[tn] = sq[j];
        lj[tn]  = plab[j];
    }

    float local = 0.f;
#pragma unroll
    for (int tm = 0; tm < 2; ++tm) {
#pragma unroll
        for (int r = 0; r < 4; ++r) {
            int i = i0 + r0 + tm * 16 + kgrp * 4 + r;
            float sqi = sq[i];
            int   li  = plab[i];
#pragma unroll
            for (int tn = 0; tn < 2; ++tn) {
                int j = j0 + c0 + tn * 16 + lrow;
                if (j > i) {
                    float d2 = fmaxf(sqi + sqj[tn] - 2.f * acc[tm][tn][r], 0.f);
                    float dist = sqrtf(d2);
                    local += (li == lj[tn]) ? (0.5f * dist)
                                            : (0.5f * fmaxf(1.f - dist, 0.f));
                }
            }
        }
    }

#pragma unroll
    for (int off = 32; off > 0; off >>= 1) local += __shfl_down(local, off);
    if (lane == 0) red[wave] = local;
    __syncthreads();
    if (threadIdx.x == 0)
        partials[blockIdx.x] = red[0] + red[1] + red[2] + red[3];
}

// ---------------------------------------------------------------------------
// reduce: 2080 partials -> out[0]
// ---------------------------------------------------------------------------
__global__ __launch_bounds__(256) void reduce_kernel(const float* __restrict__ partials,
                                                     float* __restrict__ out) {
    __shared__ float red[4];
    float s = 0.f;
    for (int i = threadIdx.x; i < NBLK; i += 256) s += partials[i];
#pragma unroll
    for (int off = 32; off > 0; off >>= 1) s += __shfl_down(s, off);
    if ((threadIdx.x & 63) == 0) red[threadIdx.x >> 6] = s;
    __syncthreads();
    if (threadIdx.x == 0)
        out[0] = (red[0] + red[1] + red[2] + red[3]) * (1.0f / B_N);
}

extern "C" void kernel_launch(void* const* d_in, const int* in_sizes, int n_in,
                              void* d_out, int out_size, void* d_ws, size_t ws_size,
                              hipStream_t stream) {
    const float* F      = (const float*)d_in[0];
    const int*   labels = (const int*)d_in[1];
    float* out = (float*)d_out;

    float*          sq    = (float*)d_ws;                                 // 16 KB
    int*            plab  = (int*)((char*)d_ws + B_N * 4);                // 16 KB
    float*          parts = (float*)((char*)d_ws + 2 * B_N * 4);          // ~8.3 KB
    unsigned short* Fb    = (unsigned short*)((char*)d_ws + 65536);       // 2 MB

    prep_kernel<<<B_N / 4, 256, 0, stream>>>(F, labels, sq, plab, Fb);
    pair_kernel<<<NBLK, 256, 0, stream>>>(Fb, sq, plab, parts);
    reduce_kernel<<<1, 256, 0, stream>>>(parts, out);
}